// Round 13
// baseline (335.431 us; speedup 1.0000x reference)
//
#include <hip/hip_runtime.h>

// DyHuCoG: out = (E + A*E + A*(A*E)) / 3
// E: [N,32] f32, A: COO (vals f32, row i32, col i32), N=100001, nE=6400000.
//
// Pipeline (atomic-free partition, 4B edges, col-split L2-resident SpMM):
//   1) tile_hist: per-4096-edge tile bucket histogram (256-row buckets)
//   2) colscan:   in-place exclusive scan down each bucket column
//   3) scan_buckets: bucket bases
//   4) partition_edges2: LDS counting-sort per tile (NO global atomics),
//      coalesced run writes of ONE uint2 array {col|rowlow<<17, q15 val}
//   5) csr_sort3: per-bucket counting sort by (rowlow, col>=half) ->
//      cv2[u32] = col | q15<<17, rowptr2[2n+1] (lo/hi segment per row)
//   6) cast emb -> bf16
//   7) layer1 in 2 phases: lo-cols -> f32 partial, hi-cols -> y1h=bf16(tot)
//      (per-phase gather set = 3.2MB, fits per-XCD L2)
//   8) layer2 in 2 phases, phase 1 fused with final combine

constexpr int D = 32;
constexpr int RPB_LOG = 8;               // rows per bucket = 256
constexpr int RPB = 1 << RPB_LOG;
constexpr int KEYS = 2 * RPB;            // (rowlow, colhalf)
constexpr int MAXNB = 512;               // supports n <= 131072 (17-bit col)
constexpr int TILE = 4096;               // edges per partition tile
constexpr int PT2 = 512;                 // partition threads
constexpr float QSCALE = 32768.0f;       // 15-bit val quantization
constexpr float QINV = 1.0f / 32768.0f;

__device__ __forceinline__ unsigned short f2bf(float f) {
    unsigned u = __float_as_uint(f);
    unsigned r = (u + 0x7FFFu + ((u >> 16) & 1u)) >> 16;   // RNE
    return (unsigned short)r;
}
__device__ __forceinline__ float bf2f(unsigned short h) {
    return __uint_as_float((unsigned)h << 16);
}

__global__ void zero_f32(float* __restrict__ p, int n) {
    int i = blockIdx.x * blockDim.x + threadIdx.x;
    if (i < n) p[i] = 0.0f;
}
__global__ void cast_bf16(const float* __restrict__ in,
                          unsigned short* __restrict__ out, int n) {
    int i = blockIdx.x * blockDim.x + threadIdx.x;
    if (i < n) out[i] = f2bf(in[i]);
}

// ------- 1) per-tile bucket histogram -> tileCnt[tile][NB] (coalesced) ----
__global__ __launch_bounds__(256) void tile_hist(
    const int* __restrict__ row, int* __restrict__ tileCnt, int nE, int NB) {
    __shared__ int h[MAXNB];
    int tile = blockIdx.x;
    int base = tile * TILE;
    int n = min(TILE, nE - base);
    int t = threadIdx.x;
    for (int i = t; i < NB; i += 256) h[i] = 0;
    __syncthreads();
    for (int i = t; i < n; i += 256)
        atomicAdd(&h[row[base + i] >> RPB_LOG], 1);
    __syncthreads();
    for (int i = t; i < NB; i += 256)
        tileCnt[(size_t)tile * NB + i] = h[i];
}

// ------- 2) in-place exclusive column scan + bucket totals ---------------
__global__ __launch_bounds__(256) void colscan(
    int* __restrict__ tileCnt, int* __restrict__ cnt, int nTiles, int NB) {
    __shared__ int s2[256];
    __shared__ int carryS;
    int b = blockIdx.x, t = threadIdx.x;
    if (t == 0) carryS = 0;
    __syncthreads();
    for (int c0 = 0; c0 < nTiles; c0 += 1024) {
        int v[4], idx[4];
        int sum = 0;
#pragma unroll
        for (int k = 0; k < 4; ++k) {
            idx[k] = c0 + t * 4 + k;
            v[k] = (idx[k] < nTiles) ? tileCnt[(size_t)idx[k] * NB + b] : 0;
            sum += v[k];
        }
        s2[t] = sum;
        __syncthreads();
        for (int o = 1; o < 256; o <<= 1) {
            int x = (t >= o) ? s2[t - o] : 0;
            __syncthreads();
            s2[t] += x;
            __syncthreads();
        }
        int run = ((t == 0) ? 0 : s2[t - 1]) + carryS;
#pragma unroll
        for (int k = 0; k < 4; ++k) {
            if (idx[k] < nTiles) tileCnt[(size_t)idx[k] * NB + b] = run;
            run += v[k];
        }
        __syncthreads();
        if (t == 0) carryS += s2[255];
        __syncthreads();
    }
    if (t == 0) cnt[b] = carryS;
}

// ---------------- 3) exclusive scan of bucket counts (NB <= 512) ---------
__global__ __launch_bounds__(512) void scan_buckets(
    const int* __restrict__ cnt, int* __restrict__ bases, int NB, int nE) {
    __shared__ int s[MAXNB];
    int t = threadIdx.x;
    s[t] = (t < NB) ? cnt[t] : 0;
    __syncthreads();
    for (int o = 1; o < 512; o <<= 1) {
        int v = (t >= o) ? s[t - o] : 0;
        __syncthreads();
        s[t] += v;
        __syncthreads();
    }
    if (t < NB) bases[t] = (t == 0) ? 0 : s[t - 1];
    if (t == 0) bases[NB] = nE;
}

// ------- 4) tiled partition, NO global atomics, coalesced writes ---------
__global__ __launch_bounds__(PT2) void partition_edges2(
    const int* __restrict__ row, const int* __restrict__ col,
    const float* __restrict__ vals, const int* __restrict__ bases,
    const int* __restrict__ tileCnt, uint2* __restrict__ cv, int nE, int NB) {
    __shared__ uint2 buf[TILE];            // 32 KB
    __shared__ unsigned short bkt[TILE];   // 8 KB
    __shared__ int hist[MAXNB];            // 2 KB (-> runbase - runoff0)
    __shared__ int runoff[MAXNB];          // 2 KB (local excl scan -> cursor)
    __shared__ int s2[PT2];                // 2 KB
    int t = threadIdx.x;
    int tile = blockIdx.x;
    int base = tile * TILE;
    int n = min(TILE, nE - base);
    if (n <= 0) return;
    for (int i = t; i < NB; i += PT2) hist[i] = 0;
    __syncthreads();
    for (int i = t; i < n; i += PT2)
        atomicAdd(&hist[row[base + i] >> RPB_LOG], 1);
    __syncthreads();
    // local exclusive scan of hist -> runoff (1 elem/thread covers 512)
    {
        int a0 = (t < NB) ? hist[t] : 0;
        s2[t] = a0;
        __syncthreads();
        for (int o = 1; o < PT2; o <<= 1) {
            int v = (t >= o) ? s2[t - o] : 0;
            __syncthreads();
            s2[t] += v;
            __syncthreads();
        }
        if (t < NB) runoff[t] = s2[t] - a0;   // exclusive
    }
    __syncthreads();
    // hist[b] := global run base - runoff0[b]
    for (int i = t; i < NB; i += PT2)
        hist[i] = bases[i] + tileCnt[(size_t)tile * NB + i] - runoff[i];
    __syncthreads();
    // reorder into LDS bucket-major
    for (int i = t; i < n; i += PT2) {
        int r = row[base + i];
        int b = r >> RPB_LOG;
        int slot = atomicAdd(&runoff[b], 1);
        float v = vals[base + i];
        int q = __float2int_rn(v * QSCALE);
        q = max(0, min(32767, q));
        uint2 p;
        p.x = (unsigned)col[base + i] | ((unsigned)(r & (RPB - 1)) << 17);
        p.y = (unsigned)q;
        buf[slot] = p;
        bkt[slot] = (unsigned short)b;
    }
    __syncthreads();
    // coalesced run writes: dest = hist[b] + slot (slot == i)
    for (int i = t; i < n; i += PT2)
        cv[hist[bkt[i]] + i] = buf[i];
}

// ------- 5) per-bucket counting sort by (rowlow, colhalf) -> CSR ---------
__global__ __launch_bounds__(512) void csr_sort3(
    const int* __restrict__ bases, const uint2* __restrict__ cv,
    unsigned* __restrict__ cv2, int* __restrict__ rowptr2,
    int n, int nE, int half) {
    __shared__ int hist_s[KEYS];
    __shared__ int cur_s[KEYS];
    int t = threadIdx.x;
    int b = blockIdx.x;
    int s = bases[b], e = bases[b + 1];
    if (t < KEYS) { hist_s[t] = 0; }
    // KEYS == 512 == blockDim, single stride
    __syncthreads();
    for (int i = s + t; i < e; i += 512) {
        unsigned x = cv[i].x;
        int key = (int)((x >> 17) << 1) | (((int)(x & 0x1FFFFu) >= half) ? 1 : 0);
        atomicAdd(&hist_s[key], 1);
    }
    __syncthreads();
    cur_s[t] = hist_s[t];
    __syncthreads();
    for (int o = 1; o < KEYS; o <<= 1) {       // inclusive scan
        int v = (t >= o) ? cur_s[t - o] : 0;
        __syncthreads();
        cur_s[t] += v;
        __syncthreads();
    }
    int excl = (t == 0) ? 0 : cur_s[t - 1];
    __syncthreads();
    {
        cur_s[t] = s + excl;
        int r = (b << RPB_LOG) + (t >> 1);
        if (r < n) rowptr2[((size_t)r << 1) | (t & 1)] = s + excl;
    }
    if (b == 0 && t == 0) rowptr2[2 * n] = nE;
    __syncthreads();
    for (int i = s + t; i < e; i += 512) {
        uint2 p = cv[i];
        unsigned x = p.x;
        int key = (int)((x >> 17) << 1) | (((int)(x & 0x1FFFFu) >= half) ? 1 : 0);
        int pos = atomicAdd(&cur_s[key], 1);
        cv2[pos] = (x & 0x1FFFFu) | (p.y << 17);
    }
}

// ---------------- gather helper (8-deep unroll) --------------------------
__device__ __forceinline__ float gather_sum(
    const unsigned* __restrict__ cv, int e, int end,
    const unsigned short* __restrict__ xh, int lane) {
    float acc = 0.0f;
    for (; e + 8 <= end; e += 8) {
        unsigned q0 = cv[e], q1 = cv[e + 1], q2 = cv[e + 2], q3 = cv[e + 3];
        unsigned q4 = cv[e + 4], q5 = cv[e + 5], q6 = cv[e + 6], q7 = cv[e + 7];
        float x0 = bf2f(xh[(size_t)(q0 & 0x1FFFFu) * D + lane]);
        float x1 = bf2f(xh[(size_t)(q1 & 0x1FFFFu) * D + lane]);
        float x2 = bf2f(xh[(size_t)(q2 & 0x1FFFFu) * D + lane]);
        float x3 = bf2f(xh[(size_t)(q3 & 0x1FFFFu) * D + lane]);
        float x4 = bf2f(xh[(size_t)(q4 & 0x1FFFFu) * D + lane]);
        float x5 = bf2f(xh[(size_t)(q5 & 0x1FFFFu) * D + lane]);
        float x6 = bf2f(xh[(size_t)(q6 & 0x1FFFFu) * D + lane]);
        float x7 = bf2f(xh[(size_t)(q7 & 0x1FFFFu) * D + lane]);
        acc += (float)(q0 >> 17) * x0;
        acc += (float)(q1 >> 17) * x1;
        acc += (float)(q2 >> 17) * x2;
        acc += (float)(q3 >> 17) * x3;
        acc += (float)(q4 >> 17) * x4;
        acc += (float)(q5 >> 17) * x5;
        acc += (float)(q6 >> 17) * x6;
        acc += (float)(q7 >> 17) * x7;
    }
    for (; e < end; ++e) {
        unsigned q = cv[e];
        acc += (float)(q >> 17) * bf2f(xh[(size_t)(q & 0x1FFFFu) * D + lane]);
    }
    return acc;
}

// ------- 7) layer-1 SpMM, 2 phases: partial f32 -> y1h bf16 --------------
template <int PHASE>
__global__ __launch_bounds__(256) void spmm_l1(
    const int* __restrict__ ptr2, const unsigned* __restrict__ cv,
    const unsigned short* __restrict__ xh, float* __restrict__ part,
    unsigned short* __restrict__ yh, int nRows) {
    int g = (blockIdx.x * 256 + threadIdx.x) >> 5;
    if (g >= nRows) return;
    int lane = threadIdx.x & 31;
    int e = ptr2[2 * g + PHASE], end = ptr2[2 * g + PHASE + 1];
    float acc = gather_sum(cv, e, end, xh, lane);
    size_t idx = (size_t)g * D + lane;
    if (PHASE == 0) {
        part[idx] = acc;
    } else {
        float tot = part[idx] + acc;
        yh[idx] = f2bf(tot * QINV);
    }
}

// ------- 8) layer-2 SpMM, 2 phases, phase 1 fused with combine -----------
template <int PHASE>
__global__ __launch_bounds__(256) void spmm_l2(
    const int* __restrict__ ptr2, const unsigned* __restrict__ cv,
    const unsigned short* __restrict__ y1h, const float* __restrict__ emb,
    float* __restrict__ part, float* __restrict__ out, int nRows) {
    int g = (blockIdx.x * 256 + threadIdx.x) >> 5;
    if (g >= nRows) return;
    int lane = threadIdx.x & 31;
    int e = ptr2[2 * g + PHASE], end = ptr2[2 * g + PHASE + 1];
    float acc = gather_sum(cv, e, end, y1h, lane);
    size_t idx = (size_t)g * D + lane;
    if (PHASE == 0) {
        part[idx] = acc;
    } else {
        out[idx] = (emb[idx] + bf2f(y1h[idx]) + (part[idx] + acc) * QINV)
                   * (1.0f / 3.0f);
    }
}

// =================== atomic fallback ===================
__global__ __launch_bounds__(256) void spmm_atomic(
    const int* __restrict__ row, const int* __restrict__ col,
    const float* __restrict__ vals, const float* __restrict__ x,
    float* __restrict__ y, int nEdges, float scale) {
    long long t = (long long)blockIdx.x * blockDim.x + threadIdx.x;
    int e = (int)(t >> 5);
    if (e >= nEdges) return;
    int d = (int)(t & 31);
    float g = vals[e] * scale * x[(long long)col[e] * D + d];
    atomicAdd(&y[(long long)row[e] * D + d], g);
}
__global__ void combine_third(const float* __restrict__ emb,
                              const float* __restrict__ y1,
                              float* __restrict__ out, int n) {
    int i = blockIdx.x * blockDim.x + threadIdx.x;
    if (i < n) out[i] = (emb[i] + y1[i]) * (1.0f / 3.0f);
}

extern "C" void kernel_launch(void* const* d_in, const int* in_sizes, int n_in,
                              void* d_out, int out_size, void* d_ws, size_t ws_size,
                              hipStream_t stream) {
    const float* emb  = (const float*)d_in[0];
    const float* vals = (const float*)d_in[1];
    const int*   row  = (const int*)d_in[2];
    const int*   col  = (const int*)d_in[3];
    float* out = (float*)d_out;

    const int nElem  = in_sizes[0];          // N * 32
    const int nEdges = in_sizes[1];
    const int n      = nElem / D;            // 100001
    const int NB     = (n + RPB - 1) >> RPB_LOG;   // 391
    const int BLK = 256;
    const int nTiles = (nEdges + TILE - 1) / TILE; // 1563
    const int half   = n / 2;

    // workspace layout:
    //   misc | cv(uint2 8B*nE) | cv2(u32 4B*nE)
    //   tileCnt aliases cv2 (dead before csr_sort3 writes cv2)
    //   y1h(2B)/embh(2B)/part(4B) alias cv (dead after csr_sort3)
    size_t off_cnt    = 0;                                    // NB ints
    size_t off_bases  = off_cnt + (size_t)NB * 4;             // NB+1 ints
    size_t off_rowptr = off_bases + (size_t)(NB + 1) * 4;     // 2n+1 ints
    size_t off_cv     = (off_rowptr + (size_t)(2 * n + 1) * 4 + 63) & ~(size_t)63;
    size_t off_cv2    = off_cv + (size_t)nEdges * 8;
    size_t need       = off_cv2 + (size_t)nEdges * 4;

    bool aliasFit   = ((size_t)nElem * 8 <= (size_t)nEdges * 8);   // y1h+embh+part
    bool tileCntFit = ((size_t)nTiles * NB * 4 <= (size_t)nEdges * 4);
    bool ok = (NB <= MAXNB) && (n <= 131072) && (ws_size >= need) &&
              aliasFit && tileCntFit;

    if (!ok) {
        // fallback: atomic-scatter path (needs nElem floats)
        if (ws_size < (size_t)nElem * 4) return;
        float* y1 = (float*)d_ws;
        zero_f32<<<(nElem + BLK - 1) / BLK, BLK, 0, stream>>>(y1, nElem);
        long long threads = (long long)nEdges * 32;
        int blocks = (int)((threads + BLK - 1) / BLK);
        spmm_atomic<<<blocks, BLK, 0, stream>>>(row, col, vals, emb, y1, nEdges, 1.0f);
        combine_third<<<(nElem + BLK - 1) / BLK, BLK, 0, stream>>>(emb, y1, out, nElem);
        spmm_atomic<<<blocks, BLK, 0, stream>>>(row, col, vals, y1, out, nEdges, 1.0f / 3.0f);
        return;
    }

    char* ws = (char*)d_ws;
    int*            cnt     = (int*)(ws + off_cnt);
    int*            bases   = (int*)(ws + off_bases);
    int*            rowptr2 = (int*)(ws + off_rowptr);
    uint2*          cv      = (uint2*)(ws + off_cv);
    unsigned*       cv2     = (unsigned*)(ws + off_cv2);
    int*            tileCnt = (int*)(ws + off_cv2);           // alias
    unsigned short* y1h     = (unsigned short*)(ws + off_cv); // alias (cv dead)
    unsigned short* embh    = (unsigned short*)(ws + off_cv + (size_t)nElem * 2);
    float*          part    = (float*)(ws + off_cv + (size_t)nElem * 4);

    // 1) per-tile histograms
    tile_hist<<<nTiles, 256, 0, stream>>>(row, tileCnt, nEdges, NB);

    // 2) column scan (in-place) + bucket totals
    colscan<<<NB, 256, 0, stream>>>(tileCnt, cnt, nTiles, NB);

    // 3) bucket bases
    scan_buckets<<<1, 512, 0, stream>>>(cnt, bases, NB, nEdges);

    // 4) atomic-free partition into bucket regions (single uint2 array)
    partition_edges2<<<nTiles, PT2, 0, stream>>>(row, col, vals, bases,
                                                 tileCnt, cv, nEdges, NB);

    // 5) per-bucket counting sort -> CSR with lo/hi col segments
    csr_sort3<<<NB, 512, 0, stream>>>(bases, cv, cv2, rowptr2, n, nEdges, half);

    // 6) embh = bf16(emb)   (cv region is dead now)
    cast_bf16<<<(nElem + BLK - 1) / BLK, BLK, 0, stream>>>(emb, embh, nElem);

    // 7) layer 1: y1h = bf16(A*E), two L2-resident phases
    int rowBlocks = (n * 32 + BLK - 1) / BLK;
    spmm_l1<0><<<rowBlocks, BLK, 0, stream>>>(rowptr2, cv2, embh, part, y1h, n);
    spmm_l1<1><<<rowBlocks, BLK, 0, stream>>>(rowptr2, cv2, embh, part, y1h, n);

    // 8) layer 2 + combine: out = (E + y1 + A*y1)/3
    spmm_l2<0><<<rowBlocks, BLK, 0, stream>>>(rowptr2, cv2, y1h, emb, part, out, n);
    spmm_l2<1><<<rowBlocks, BLK, 0, stream>>>(rowptr2, cv2, y1h, emb, part, out, n);
}

// Round 14
// 272.394 us; speedup vs baseline: 1.2314x; 1.2314x over previous
//
#include <hip/hip_runtime.h>

// DyHuCoG: out = (E + A*E + A*(A*E)) / 3
// E: [N,32] f32, A: COO (vals f32, row i32, col i32), N=100001, nE=6400000.
//
// Pipeline (atomic-free partition, 4B edges, LDS-staged CSR sort):
//   1) tile_hist: per-4096-edge tile bucket histogram (256-row buckets)
//   2) colscan:   in-place exclusive scan down each bucket column
//   3) scan_buckets: bucket bases
//   4) partition_edges2: LDS counting-sort per tile (NO global atomics),
//      coalesced run writes of ONE uint2 array {col|rowlow<<17, q15 val}
//   5) csr_sort4: per bucket-HALF (128 rows), read bucket twice, LDS-stage
//      the counting sort, write cv2 runs coalesced (no scattered writes)
//   6) cast emb -> bf16
//   7) y1h = bf16(A*E)      gather SpMM (bf16 gathers, f32 accumulate)
//   8) out = (E + y1 + A*y1)/3  fused layer-2 SpMM + combine

constexpr int D = 32;
constexpr int RPB_LOG = 8;               // rows per bucket = 256
constexpr int RPB = 1 << RPB_LOG;
constexpr int MAXNB = 512;               // supports n <= 131072 (17-bit col)
constexpr int TILE = 4096;               // edges per partition tile
constexpr int PT2 = 512;                 // partition threads
constexpr int CAP = 9728;                // LDS staging capacity (edges/half)
constexpr float QSCALE = 32768.0f;       // 15-bit val quantization
constexpr float QINV = 1.0f / 32768.0f;

__device__ __forceinline__ unsigned short f2bf(float f) {
    unsigned u = __float_as_uint(f);
    unsigned r = (u + 0x7FFFu + ((u >> 16) & 1u)) >> 16;   // RNE
    return (unsigned short)r;
}
__device__ __forceinline__ float bf2f(unsigned short h) {
    return __uint_as_float((unsigned)h << 16);
}

__global__ void zero_f32(float* __restrict__ p, int n) {
    int i = blockIdx.x * blockDim.x + threadIdx.x;
    if (i < n) p[i] = 0.0f;
}
__global__ void cast_bf16(const float* __restrict__ in,
                          unsigned short* __restrict__ out, int n) {
    int i = blockIdx.x * blockDim.x + threadIdx.x;
    if (i < n) out[i] = f2bf(in[i]);
}

// ------- 1) per-tile bucket histogram -> tileCnt[tile][NB] (coalesced) ----
__global__ __launch_bounds__(256) void tile_hist(
    const int* __restrict__ row, int* __restrict__ tileCnt, int nE, int NB) {
    __shared__ int h[MAXNB];
    int tile = blockIdx.x;
    int base = tile * TILE;
    int n = min(TILE, nE - base);
    int t = threadIdx.x;
    for (int i = t; i < NB; i += 256) h[i] = 0;
    __syncthreads();
    for (int i = t; i < n; i += 256)
        atomicAdd(&h[row[base + i] >> RPB_LOG], 1);
    __syncthreads();
    for (int i = t; i < NB; i += 256)
        tileCnt[(size_t)tile * NB + i] = h[i];
}

// ------- 2) in-place exclusive column scan + bucket totals ---------------
__global__ __launch_bounds__(256) void colscan(
    int* __restrict__ tileCnt, int* __restrict__ cnt, int nTiles, int NB) {
    __shared__ int s2[256];
    __shared__ int carryS;
    int b = blockIdx.x, t = threadIdx.x;
    if (t == 0) carryS = 0;
    __syncthreads();
    for (int c0 = 0; c0 < nTiles; c0 += 1024) {
        int v[4], idx[4];
        int sum = 0;
#pragma unroll
        for (int k = 0; k < 4; ++k) {
            idx[k] = c0 + t * 4 + k;
            v[k] = (idx[k] < nTiles) ? tileCnt[(size_t)idx[k] * NB + b] : 0;
            sum += v[k];
        }
        s2[t] = sum;
        __syncthreads();
        for (int o = 1; o < 256; o <<= 1) {
            int x = (t >= o) ? s2[t - o] : 0;
            __syncthreads();
            s2[t] += x;
            __syncthreads();
        }
        int run = ((t == 0) ? 0 : s2[t - 1]) + carryS;
#pragma unroll
        for (int k = 0; k < 4; ++k) {
            if (idx[k] < nTiles) tileCnt[(size_t)idx[k] * NB + b] = run;
            run += v[k];
        }
        __syncthreads();
        if (t == 0) carryS += s2[255];
        __syncthreads();
    }
    if (t == 0) cnt[b] = carryS;
}

// ---------------- 3) exclusive scan of bucket counts (NB <= 512) ---------
__global__ __launch_bounds__(512) void scan_buckets(
    const int* __restrict__ cnt, int* __restrict__ bases, int NB, int nE) {
    __shared__ int s[MAXNB];
    int t = threadIdx.x;
    s[t] = (t < NB) ? cnt[t] : 0;
    __syncthreads();
    for (int o = 1; o < 512; o <<= 1) {
        int v = (t >= o) ? s[t - o] : 0;
        __syncthreads();
        s[t] += v;
        __syncthreads();
    }
    if (t < NB) bases[t] = (t == 0) ? 0 : s[t - 1];
    if (t == 0) bases[NB] = nE;
}

// ------- 4) tiled partition, NO global atomics, coalesced writes ---------
__global__ __launch_bounds__(PT2) void partition_edges2(
    const int* __restrict__ row, const int* __restrict__ col,
    const float* __restrict__ vals, const int* __restrict__ bases,
    const int* __restrict__ tileCnt, uint2* __restrict__ cv, int nE, int NB) {
    __shared__ uint2 buf[TILE];            // 32 KB
    __shared__ unsigned short bkt[TILE];   // 8 KB
    __shared__ int hist[MAXNB];            // 2 KB (-> runbase - runoff0)
    __shared__ int runoff[MAXNB];          // 2 KB (local excl scan -> cursor)
    __shared__ int s2[PT2];                // 2 KB
    int t = threadIdx.x;
    int tile = blockIdx.x;
    int base = tile * TILE;
    int n = min(TILE, nE - base);
    if (n <= 0) return;
    for (int i = t; i < NB; i += PT2) hist[i] = 0;
    __syncthreads();
    for (int i = t; i < n; i += PT2)
        atomicAdd(&hist[row[base + i] >> RPB_LOG], 1);
    __syncthreads();
    // local exclusive scan of hist -> runoff (1 elem/thread covers 512)
    {
        int a0 = (t < NB) ? hist[t] : 0;
        s2[t] = a0;
        __syncthreads();
        for (int o = 1; o < PT2; o <<= 1) {
            int v = (t >= o) ? s2[t - o] : 0;
            __syncthreads();
            s2[t] += v;
            __syncthreads();
        }
        if (t < NB) runoff[t] = s2[t] - a0;   // exclusive
    }
    __syncthreads();
    // hist[b] := global run base - runoff0[b]
    for (int i = t; i < NB; i += PT2)
        hist[i] = bases[i] + tileCnt[(size_t)tile * NB + i] - runoff[i];
    __syncthreads();
    // reorder into LDS bucket-major
    for (int i = t; i < n; i += PT2) {
        int r = row[base + i];
        int b = r >> RPB_LOG;
        int slot = atomicAdd(&runoff[b], 1);
        float v = vals[base + i];
        int q = __float2int_rn(v * QSCALE);
        q = max(0, min(32767, q));
        uint2 p;
        p.x = (unsigned)col[base + i] | ((unsigned)(r & (RPB - 1)) << 17);
        p.y = (unsigned)q;
        buf[slot] = p;
        bkt[slot] = (unsigned short)b;
    }
    __syncthreads();
    // coalesced run writes: dest = hist[b] + slot (slot == i)
    for (int i = t; i < n; i += PT2)
        cv[hist[bkt[i]] + i] = buf[i];
}

// ------- 5) per bucket-half LDS-staged counting sort -> exact CSR --------
// Block (b, h): rows [h*128, h*128+128) of bucket b. Reads the bucket's
// edge range twice (sequential); writes its output range coalesced.
__global__ __launch_bounds__(512) void csr_sort4(
    const int* __restrict__ bases, const uint2* __restrict__ cv,
    unsigned* __restrict__ cv2, int* __restrict__ rowptr, int n, int nE) {
    __shared__ unsigned stage[CAP];        // 38 KB
    __shared__ int hist_s[RPB];            // 1 KB
    __shared__ int cur_s[RPB];             // 1 KB
    int t = threadIdx.x;
    int b = blockIdx.x >> 1;
    int h = blockIdx.x & 1;
    int s = bases[b], e = bases[b + 1];
    if (t < RPB) hist_s[t] = 0;
    __syncthreads();
    // pass 1: full-bucket histogram (both halves, for prefix)
    for (int i = s + t; i < e; i += 512)
        atomicAdd(&hist_s[cv[i].x >> 17], 1);
    __syncthreads();
    if (t < RPB) cur_s[t] = hist_s[t];
    __syncthreads();
    for (int o = 1; o < RPB; o <<= 1) {       // inclusive scan
        int v = 0;
        if (t < RPB && t >= o) v = cur_s[t - o];
        __syncthreads();
        if (t < RPB) cur_s[t] += v;
        __syncthreads();
    }
    // exclusive prefix per row (register), half boundaries
    int excl = 0;
    if (t < RPB) excl = (t == 0) ? 0 : cur_s[t - 1];
    int half_lo = h << 7;                     // h*128
    __syncthreads();
    int base_h = (half_lo == 0) ? 0 : cur_s[half_lo - 1];
    int end_h  = cur_s[half_lo + 127];
    int cnt_h  = end_h - base_h;
    __syncthreads();
    if (t < RPB) {
        // rowptr for own half only
        if ((t >> 7) == h) {
            int r = (b << RPB_LOG) + t;
            if (r < n) rowptr[r] = s + excl;
            cur_s[t] = excl - base_h;         // local staging cursor
        }
    }
    if (b == 0 && h == 0 && t == 0) rowptr[n] = nE;
    __syncthreads();
    bool fits = (cnt_h <= CAP);
    // pass 2: re-read, keep own half, stage (or direct-scatter on overflow)
    for (int i = s + t; i < e; i += 512) {
        uint2 p = cv[i];
        int r = (int)(p.x >> 17);
        if ((r >> 7) != h) continue;
        int slot = atomicAdd(&cur_s[r], 1);
        unsigned packed = (p.x & 0x1FFFFu) | (p.y << 17);
        if (fits) stage[slot] = packed;
        else      cv2[s + base_h + slot] = packed;
    }
    __syncthreads();
    // pass 3: coalesced run write
    if (fits) {
        int dst = s + base_h;
        for (int j = t; j < cnt_h; j += 512)
            cv2[dst + j] = stage[j];
    }
}

// ---------------- 7) layer-1 SpMM: y1h = bf16(A*E) -----------------------
__global__ __launch_bounds__(256) void spmm_l1(
    const int* __restrict__ ptr, const unsigned* __restrict__ cv,
    const unsigned short* __restrict__ xh, unsigned short* __restrict__ yh,
    int nRows) {
    int g = (blockIdx.x * 256 + threadIdx.x) >> 5;
    if (g >= nRows) return;
    int lane = threadIdx.x & 31;
    int e = ptr[g], end = ptr[g + 1];
    float acc = 0.0f;
    for (; e + 8 <= end; e += 8) {
        unsigned q0 = cv[e], q1 = cv[e + 1], q2 = cv[e + 2], q3 = cv[e + 3];
        unsigned q4 = cv[e + 4], q5 = cv[e + 5], q6 = cv[e + 6], q7 = cv[e + 7];
        float x0 = bf2f(xh[(size_t)(q0 & 0x1FFFFu) * D + lane]);
        float x1 = bf2f(xh[(size_t)(q1 & 0x1FFFFu) * D + lane]);
        float x2 = bf2f(xh[(size_t)(q2 & 0x1FFFFu) * D + lane]);
        float x3 = bf2f(xh[(size_t)(q3 & 0x1FFFFu) * D + lane]);
        float x4 = bf2f(xh[(size_t)(q4 & 0x1FFFFu) * D + lane]);
        float x5 = bf2f(xh[(size_t)(q5 & 0x1FFFFu) * D + lane]);
        float x6 = bf2f(xh[(size_t)(q6 & 0x1FFFFu) * D + lane]);
        float x7 = bf2f(xh[(size_t)(q7 & 0x1FFFFu) * D + lane]);
        acc += (float)(q0 >> 17) * x0;
        acc += (float)(q1 >> 17) * x1;
        acc += (float)(q2 >> 17) * x2;
        acc += (float)(q3 >> 17) * x3;
        acc += (float)(q4 >> 17) * x4;
        acc += (float)(q5 >> 17) * x5;
        acc += (float)(q6 >> 17) * x6;
        acc += (float)(q7 >> 17) * x7;
    }
    for (; e < end; ++e) {
        unsigned q = cv[e];
        acc += (float)(q >> 17) * bf2f(xh[(size_t)(q & 0x1FFFFu) * D + lane]);
    }
    yh[(size_t)g * D + lane] = f2bf(acc * QINV);
}

// ------- 8) layer-2 SpMM fused with combine: out=(emb+y1+A*y1)/3 ---------
__global__ __launch_bounds__(256) void spmm_combine(
    const int* __restrict__ ptr, const unsigned* __restrict__ cv,
    const unsigned short* __restrict__ y1h, const float* __restrict__ emb,
    float* __restrict__ out, int nRows) {
    int g = (blockIdx.x * 256 + threadIdx.x) >> 5;
    if (g >= nRows) return;
    int lane = threadIdx.x & 31;
    int e = ptr[g], end = ptr[g + 1];
    float acc = 0.0f;
    for (; e + 8 <= end; e += 8) {
        unsigned q0 = cv[e], q1 = cv[e + 1], q2 = cv[e + 2], q3 = cv[e + 3];
        unsigned q4 = cv[e + 4], q5 = cv[e + 5], q6 = cv[e + 6], q7 = cv[e + 7];
        float x0 = bf2f(y1h[(size_t)(q0 & 0x1FFFFu) * D + lane]);
        float x1 = bf2f(y1h[(size_t)(q1 & 0x1FFFFu) * D + lane]);
        float x2 = bf2f(y1h[(size_t)(q2 & 0x1FFFFu) * D + lane]);
        float x3 = bf2f(y1h[(size_t)(q3 & 0x1FFFFu) * D + lane]);
        float x4 = bf2f(y1h[(size_t)(q4 & 0x1FFFFu) * D + lane]);
        float x5 = bf2f(y1h[(size_t)(q5 & 0x1FFFFu) * D + lane]);
        float x6 = bf2f(y1h[(size_t)(q6 & 0x1FFFFu) * D + lane]);
        float x7 = bf2f(y1h[(size_t)(q7 & 0x1FFFFu) * D + lane]);
        acc += (float)(q0 >> 17) * x0;
        acc += (float)(q1 >> 17) * x1;
        acc += (float)(q2 >> 17) * x2;
        acc += (float)(q3 >> 17) * x3;
        acc += (float)(q4 >> 17) * x4;
        acc += (float)(q5 >> 17) * x5;
        acc += (float)(q6 >> 17) * x6;
        acc += (float)(q7 >> 17) * x7;
    }
    for (; e < end; ++e) {
        unsigned q = cv[e];
        acc += (float)(q >> 17) * bf2f(y1h[(size_t)(q & 0x1FFFFu) * D + lane]);
    }
    size_t idx = (size_t)g * D + lane;
    out[idx] = (emb[idx] + bf2f(y1h[idx]) + acc * QINV) * (1.0f / 3.0f);
}

// =================== atomic fallback ===================
__global__ __launch_bounds__(256) void spmm_atomic(
    const int* __restrict__ row, const int* __restrict__ col,
    const float* __restrict__ vals, const float* __restrict__ x,
    float* __restrict__ y, int nEdges, float scale) {
    long long t = (long long)blockIdx.x * blockDim.x + threadIdx.x;
    int e = (int)(t >> 5);
    if (e >= nEdges) return;
    int d = (int)(t & 31);
    float g = vals[e] * scale * x[(long long)col[e] * D + d];
    atomicAdd(&y[(long long)row[e] * D + d], g);
}
__global__ void combine_third(const float* __restrict__ emb,
                              const float* __restrict__ y1,
                              float* __restrict__ out, int n) {
    int i = blockIdx.x * blockDim.x + threadIdx.x;
    if (i < n) out[i] = (emb[i] + y1[i]) * (1.0f / 3.0f);
}

extern "C" void kernel_launch(void* const* d_in, const int* in_sizes, int n_in,
                              void* d_out, int out_size, void* d_ws, size_t ws_size,
                              hipStream_t stream) {
    const float* emb  = (const float*)d_in[0];
    const float* vals = (const float*)d_in[1];
    const int*   row  = (const int*)d_in[2];
    const int*   col  = (const int*)d_in[3];
    float* out = (float*)d_out;

    const int nElem  = in_sizes[0];          // N * 32
    const int nEdges = in_sizes[1];
    const int n      = nElem / D;            // 100001
    const int NB     = (n + RPB - 1) >> RPB_LOG;   // 391
    const int BLK = 256;
    const int nTiles = (nEdges + TILE - 1) / TILE; // 1563

    // workspace layout:
    //   misc | cv(uint2 8B*nE) | cv2(u32 4B*nE)
    //   tileCnt aliases cv2 (dead before csr_sort4 writes cv2)
    //   y1h/embh alias cv (dead after csr_sort4)
    size_t off_cnt    = 0;                                    // NB ints
    size_t off_bases  = off_cnt + (size_t)NB * 4;             // NB+1 ints
    size_t off_rowptr = off_bases + (size_t)(NB + 1) * 4;     // n+1 ints
    size_t off_cv     = (off_rowptr + (size_t)(n + 1) * 4 + 63) & ~(size_t)63;
    size_t off_cv2    = off_cv + (size_t)nEdges * 8;
    size_t need       = off_cv2 + (size_t)nEdges * 4;

    bool aliasFit   = ((size_t)nElem * 4 <= (size_t)nEdges * 8);   // y1h+embh in cv
    bool tileCntFit = ((size_t)nTiles * NB * 4 <= (size_t)nEdges * 4);
    bool ok = (NB <= MAXNB) && (n <= 131072) && (ws_size >= need) &&
              aliasFit && tileCntFit;

    if (!ok) {
        // fallback: atomic-scatter path (needs nElem floats)
        if (ws_size < (size_t)nElem * 4) return;
        float* y1 = (float*)d_ws;
        zero_f32<<<(nElem + BLK - 1) / BLK, BLK, 0, stream>>>(y1, nElem);
        long long threads = (long long)nEdges * 32;
        int blocks = (int)((threads + BLK - 1) / BLK);
        spmm_atomic<<<blocks, BLK, 0, stream>>>(row, col, vals, emb, y1, nEdges, 1.0f);
        combine_third<<<(nElem + BLK - 1) / BLK, BLK, 0, stream>>>(emb, y1, out, nElem);
        spmm_atomic<<<blocks, BLK, 0, stream>>>(row, col, vals, y1, out, nEdges, 1.0f / 3.0f);
        return;
    }

    char* ws = (char*)d_ws;
    int*            cnt     = (int*)(ws + off_cnt);
    int*            bases   = (int*)(ws + off_bases);
    int*            rowptr  = (int*)(ws + off_rowptr);
    uint2*          cv      = (uint2*)(ws + off_cv);
    unsigned*       cv2     = (unsigned*)(ws + off_cv2);
    int*            tileCnt = (int*)(ws + off_cv2);           // alias
    unsigned short* y1h     = (unsigned short*)(ws + off_cv); // alias (cv dead)
    unsigned short* embh    = (unsigned short*)(ws + off_cv + (size_t)nElem * 2);

    // 1) per-tile histograms
    tile_hist<<<nTiles, 256, 0, stream>>>(row, tileCnt, nEdges, NB);

    // 2) column scan (in-place) + bucket totals
    colscan<<<NB, 256, 0, stream>>>(tileCnt, cnt, nTiles, NB);

    // 3) bucket bases
    scan_buckets<<<1, 512, 0, stream>>>(cnt, bases, NB, nEdges);

    // 4) atomic-free partition into bucket regions (single uint2 array)
    partition_edges2<<<nTiles, PT2, 0, stream>>>(row, col, vals, bases,
                                                 tileCnt, cv, nEdges, NB);

    // 5) per bucket-half LDS-staged counting sort -> exact CSR
    csr_sort4<<<2 * NB, 512, 0, stream>>>(bases, cv, cv2, rowptr, n, nEdges);

    // 6) embh = bf16(emb)   (cv region is dead now)
    cast_bf16<<<(nElem + BLK - 1) / BLK, BLK, 0, stream>>>(emb, embh, nElem);

    // 7) y1h = bf16(A*E)
    int rowBlocks = (n * 32 + BLK - 1) / BLK;
    spmm_l1<<<rowBlocks, BLK, 0, stream>>>(rowptr, cv2, embh, y1h, n);

    // 8) out = (E + y1 + A*y1)/3
    spmm_combine<<<rowBlocks, BLK, 0, stream>>>(rowptr, cv2, y1h, emb, out, n);
}